// Round 3
// baseline (1526.849 us; speedup 1.0000x reference)
//
#include <hip/hip_runtime.h>
#include <hip/hip_bf16.h>
#include <cstdint>

typedef unsigned short ushort_t;
typedef __bf16  bf16x8 __attribute__((ext_vector_type(8)));
typedef float   f32x4  __attribute__((ext_vector_type(4)));

#define L_SEQ 2048
#define C_DIM 512
#define B_SZ  8
#define N_GROUPS 8
#define CG 64            // C / GROUPS

__device__ __forceinline__ float bf2f(ushort_t u) {
    union { uint32_t i; float f; } x; x.i = ((uint32_t)u) << 16; return x.f;
}
__device__ __forceinline__ ushort_t f2bf(float f) {
    union { float f; uint32_t i; } x; x.f = f;
    uint32_t i = x.i;
    uint32_t r = (i + 0x7FFFu + ((i >> 16) & 1u)) >> 16;
    return (ushort_t)r;
}

// ---------------- convert 4 weight matrices fp32 -> bf16 ----------------
// grid 512: 128 blocks per weight, 256 thr x 8 elems = 2048 elems/block.
__global__ __launch_bounds__(256) void conv_w(const float* __restrict__ wq,
                                              const float* __restrict__ wk,
                                              const float* __restrict__ wv,
                                              const float* __restrict__ wp,
                                              ushort_t* __restrict__ owq,
                                              ushort_t* __restrict__ owk,
                                              ushort_t* __restrict__ owv,
                                              ushort_t* __restrict__ owp) {
    int blk = blockIdx.x, tid = threadIdx.x;
    int seg = blk >> 7;
    const float* srcs[4] = {wq, wk, wv, wp};
    ushort_t*    dsts[4] = {owq, owk, owv, owp};
    const float* src = srcs[seg];
    ushort_t*    dst = dsts[seg];
    int off = (blk & 127) * 2048 + tid * 8;
    float4 a = *(const float4*)(src + off);
    float4 b = *(const float4*)(src + off + 4);
    union { uint4 v; ushort_t u[8]; } o;
    o.u[0] = f2bf(a.x); o.u[1] = f2bf(a.y); o.u[2] = f2bf(a.z); o.u[3] = f2bf(a.w);
    o.u[4] = f2bf(b.x); o.u[5] = f2bf(b.y); o.u[6] = f2bf(b.z); o.u[7] = f2bf(b.w);
    *(uint4*)(dst + off) = o.v;
}

// ---------------- GroupNorm stats (fp32 x, split-L partials) ----------------
// grid = 64 (b,g) * 8 splits; sums layout [bg][split][2]
__global__ __launch_bounds__(256) void gn_stats(const float* __restrict__ x,
                                                float* __restrict__ sums) {
    int bg = blockIdx.x >> 3, sp = blockIdx.x & 7;
    int b = bg >> 3, g = bg & 7;
    int tid = threadIdx.x;
    const float* base = x + ((size_t)b * L_SEQ + sp * 256) * C_DIM + g * CG;
    float s = 0.f, s2 = 0.f;
    #pragma unroll
    for (int it = 0; it < 8; ++it) {
        int i = it * 2048 + tid * 8;      // within [256 rows][64 ch]
        int l = i >> 6, c = i & 63;
        const float* p = base + (size_t)l * C_DIM + c;
        float4 a = *(const float4*)p;
        float4 bb = *(const float4*)(p + 4);
        s  += a.x + a.y + a.z + a.w + bb.x + bb.y + bb.z + bb.w;
        s2 += a.x*a.x + a.y*a.y + a.z*a.z + a.w*a.w
            + bb.x*bb.x + bb.y*bb.y + bb.z*bb.z + bb.w*bb.w;
    }
    #pragma unroll
    for (int off = 32; off > 0; off >>= 1) { s += __shfl_down(s, off); s2 += __shfl_down(s2, off); }
    __shared__ float rs[4], rs2[4];
    int wave = tid >> 6;
    if ((tid & 63) == 0) { rs[wave] = s; rs2[wave] = s2; }
    __syncthreads();
    if (tid == 0) {
        sums[bg * 16 + sp * 2 + 0] = rs[0] + rs[1] + rs[2] + rs[3];
        sums[bg * 16 + sp * 2 + 1] = rs2[0] + rs2[1] + rs2[2] + rs2[3];
    }
}

// ---------------- GroupNorm apply: fp32 x -> bf16 h ----------------
__global__ __launch_bounds__(256) void gn_apply(const float* __restrict__ x,
                                                const float* __restrict__ gamma,
                                                const float* __restrict__ beta,
                                                const float* __restrict__ sums,
                                                ushort_t* __restrict__ h) {
    size_t e = ((size_t)blockIdx.x * 256 + threadIdx.x) * 8;
    int c = (int)(e % C_DIM);
    size_t bl = e / C_DIM;
    int b = (int)(bl / L_SEQ);
    int g = c >> 6;
    int bg = b * 8 + g;
    float s = 0.f, s2 = 0.f;
    #pragma unroll
    for (int sp = 0; sp < 8; ++sp) { s += sums[bg * 16 + sp * 2]; s2 += sums[bg * 16 + sp * 2 + 1]; }
    const float N = (float)(L_SEQ * CG);
    float mean = s / N;
    float var  = s2 / N - mean * mean;
    float rstd = rsqrtf(var + 1e-3f);
    float4 a = *(const float4*)(x + e);
    float4 bb = *(const float4*)(x + e + 4);
    float xf[8] = {a.x, a.y, a.z, a.w, bb.x, bb.y, bb.z, bb.w};
    union { uint4 v; ushort_t u[8]; } o;
    #pragma unroll
    for (int i = 0; i < 8; ++i)
        o.u[i] = f2bf((xf[i] - mean) * rstd * gamma[c + i] + beta[c + i]);
    *(uint4*)(h + e) = o.v;
}

// ---------------- GEMM: out[m][n] = sum_k A[m][k] W[k][n] + bias[n] (+ res[m][n]) ----------------
// M = grid.y*64, N=512 (grid.x=8), K=512. Block 256 thr = 4 waves, 64x64 tile.
// F32OUT: write fp32 (final output), else bf16 (ws intermediates).
template<bool F32OUT>
__global__ __launch_bounds__(256) void gemm_bias(const ushort_t* __restrict__ A,
                                                 const ushort_t* __restrict__ W,
                                                 const float* __restrict__ bias,
                                                 const ushort_t* __restrict__ res,
                                                 void* __restrict__ outv) {
    __shared__ ushort_t As[64][40];   // [m][k] pad 32->40
    __shared__ ushort_t Bt[64][40];   // [n][k] pad 32->40 (transposed store)
    int tid = threadIdx.x;
    int m0 = blockIdx.y * 64, n0 = blockIdx.x * 64;
    int lane = tid & 63, w = tid >> 6;
    int wm = w >> 1, wn = w & 1;
    int l15 = lane & 15, quad = lane >> 4;
    f32x4 acc[2][2] = {};
    int arow = tid >> 2, acol = (tid & 3) * 8;
    int brow = tid >> 3, bcol = (tid & 7) * 8;
    for (int k0 = 0; k0 < 512; k0 += 32) {
        union { uint4 v; ushort_t u[8]; } da, db;
        da.v = *(const uint4*)(A + (size_t)(m0 + arow) * 512 + k0 + acol);
        db.v = *(const uint4*)(W + (size_t)(k0 + brow) * 512 + n0 + bcol);
        *(uint4*)&As[arow][acol] = da.v;
        #pragma unroll
        for (int e = 0; e < 8; ++e) Bt[bcol + e][brow] = db.u[e];
        __syncthreads();
        bf16x8 af0 = *(const bf16x8*)&As[wm * 32 + l15][quad * 8];
        bf16x8 af1 = *(const bf16x8*)&As[wm * 32 + 16 + l15][quad * 8];
        bf16x8 bf0 = *(const bf16x8*)&Bt[wn * 32 + l15][quad * 8];
        bf16x8 bf1 = *(const bf16x8*)&Bt[wn * 32 + 16 + l15][quad * 8];
        acc[0][0] = __builtin_amdgcn_mfma_f32_16x16x32_bf16(af0, bf0, acc[0][0], 0, 0, 0);
        acc[0][1] = __builtin_amdgcn_mfma_f32_16x16x32_bf16(af0, bf1, acc[0][1], 0, 0, 0);
        acc[1][0] = __builtin_amdgcn_mfma_f32_16x16x32_bf16(af1, bf0, acc[1][0], 0, 0, 0);
        acc[1][1] = __builtin_amdgcn_mfma_f32_16x16x32_bf16(af1, bf1, acc[1][1], 0, 0, 0);
        __syncthreads();
    }
    #pragma unroll
    for (int mt = 0; mt < 2; ++mt)
        #pragma unroll
        for (int nt = 0; nt < 2; ++nt)
            #pragma unroll
            for (int r = 0; r < 4; ++r) {
                int m = m0 + wm * 32 + mt * 16 + quad * 4 + r;
                int n = n0 + wn * 32 + nt * 16 + l15;
                float v = acc[mt][nt][r] + bias[n];
                if (res) v += bf2f(res[(size_t)m * 512 + n]);
                if (F32OUT) ((float*)outv)[(size_t)m * 512 + n] = v;
                else        ((ushort_t*)outv)[(size_t)m * 512 + n] = f2bf(v);
            }
}

// ---------------- Flash attention: d=512, L=2048, per-batch; Q-tile 32, K-tile 32 ----------------
// grid = (64 q-tiles, 8 batches), 256 threads (4 waves).
// Wave w: QK^T partial over c in [w*128,(w+1)*128); PV over d in [w*128,(w+1)*128).
__global__ __launch_bounds__(256) void attn_kernel(const ushort_t* __restrict__ Q,
                                                   const ushort_t* __restrict__ K,
                                                   const ushort_t* __restrict__ V,
                                                   ushort_t* __restrict__ O) {
    __shared__ ushort_t Vt[512][40];        // V transposed: Vt[d][k], pad 32->40
    __shared__ float Sp[4][32][33];         // per-wave S partials
    __shared__ ushort_t Ps[32][40];         // P (bf16) pad 32->40
    __shared__ float m_l[32], l_l[32], al_l[32];
    int tid = threadIdx.x;
    int qt = blockIdx.x, b = blockIdx.y;
    int q0 = qt * 32;
    int lane = tid & 63, w = tid >> 6;
    int l15 = lane & 15, quad = lane >> 4;
    int cb = w * 128;
    const float scale = 0.044194173824159216f;  // 512^-0.5
    const ushort_t* Qb = Q + (size_t)b * L_SEQ * C_DIM;
    const ushort_t* Kb = K + (size_t)b * L_SEQ * C_DIM;
    const ushort_t* Vb = V + (size_t)b * L_SEQ * C_DIM;
    ushort_t* Ob = O + (size_t)b * L_SEQ * C_DIM;

    bf16x8 qf[2][4];
    #pragma unroll
    for (int mt = 0; mt < 2; ++mt)
        #pragma unroll
        for (int cs = 0; cs < 4; ++cs)
            qf[mt][cs] = *(const bf16x8*)(Qb + (size_t)(q0 + mt * 16 + l15) * 512 + cb + cs * 32 + quad * 8);

    f32x4 acc[2][8] = {};
    if (tid < 32) { m_l[tid] = -1e30f; l_l[tid] = 0.f; }
    __syncthreads();

    for (int kt = 0; kt < 64; ++kt) {
        int k0 = kt * 32;
        // stage V transposed into LDS
        #pragma unroll
        for (int it = 0; it < 8; ++it) {
            int i = it * 256 + tid;
            int row = i >> 6, col8 = (i & 63) * 8;
            union { uint4 v; ushort_t u[8]; } d;
            d.v = *(const uint4*)(Vb + (size_t)(k0 + row) * 512 + col8);
            #pragma unroll
            for (int e = 0; e < 8; ++e) Vt[col8 + e][row] = d.u[e];
        }
        // S partial = Q[:, cb:cb+128] @ K[:, cb:cb+128]^T  (K frags direct from global)
        f32x4 sacc[2][2] = {};
        #pragma unroll
        for (int cs = 0; cs < 4; ++cs) {
            bf16x8 kf0 = *(const bf16x8*)(Kb + (size_t)(k0 + l15) * 512 + cb + cs * 32 + quad * 8);
            bf16x8 kf1 = *(const bf16x8*)(Kb + (size_t)(k0 + 16 + l15) * 512 + cb + cs * 32 + quad * 8);
            sacc[0][0] = __builtin_amdgcn_mfma_f32_16x16x32_bf16(qf[0][cs], kf0, sacc[0][0], 0, 0, 0);
            sacc[0][1] = __builtin_amdgcn_mfma_f32_16x16x32_bf16(qf[0][cs], kf1, sacc[0][1], 0, 0, 0);
            sacc[1][0] = __builtin_amdgcn_mfma_f32_16x16x32_bf16(qf[1][cs], kf0, sacc[1][0], 0, 0, 0);
            sacc[1][1] = __builtin_amdgcn_mfma_f32_16x16x32_bf16(qf[1][cs], kf1, sacc[1][1], 0, 0, 0);
        }
        #pragma unroll
        for (int mt = 0; mt < 2; ++mt)
            #pragma unroll
            for (int nt = 0; nt < 2; ++nt)
                #pragma unroll
                for (int r = 0; r < 4; ++r)
                    Sp[w][mt * 16 + quad * 4 + r][nt * 16 + l15] = sacc[mt][nt][r];
        __syncthreads();
        // online softmax (one thread per query row)
        if (tid < 32) {
            int r = tid;
            float mo = m_l[r], mn = mo;
            float sv[32];
            #pragma unroll
            for (int c = 0; c < 32; ++c) {
                sv[c] = scale * (Sp[0][r][c] + Sp[1][r][c] + Sp[2][r][c] + Sp[3][r][c]);
                mn = fmaxf(mn, sv[c]);
            }
            float alpha = __expf(mo - mn);
            float ls = 0.f;
            #pragma unroll
            for (int c = 0; c < 32; ++c) {
                ushort_t pb = f2bf(__expf(sv[c] - mn));
                Ps[r][c] = pb;
                ls += bf2f(pb);
            }
            m_l[r] = mn;
            l_l[r] = l_l[r] * alpha + ls;
            al_l[r] = alpha;
        }
        __syncthreads();
        // rescale O by alpha, then O += P @ V_tile (wave's 128-wide d-chunk)
        bf16x8 pf[2];
        #pragma unroll
        for (int mt = 0; mt < 2; ++mt) pf[mt] = *(const bf16x8*)&Ps[mt * 16 + l15][quad * 8];
        #pragma unroll
        for (int mt = 0; mt < 2; ++mt) {
            float a0 = al_l[mt * 16 + quad * 4 + 0];
            float a1 = al_l[mt * 16 + quad * 4 + 1];
            float a2 = al_l[mt * 16 + quad * 4 + 2];
            float a3 = al_l[mt * 16 + quad * 4 + 3];
            #pragma unroll
            for (int nt = 0; nt < 8; ++nt) {
                acc[mt][nt][0] *= a0; acc[mt][nt][1] *= a1;
                acc[mt][nt][2] *= a2; acc[mt][nt][3] *= a3;
            }
        }
        #pragma unroll
        for (int nt = 0; nt < 8; ++nt) {
            bf16x8 vf = *(const bf16x8*)&Vt[cb + nt * 16 + l15][quad * 8];
            acc[0][nt] = __builtin_amdgcn_mfma_f32_16x16x32_bf16(pf[0], vf, acc[0][nt], 0, 0, 0);
            acc[1][nt] = __builtin_amdgcn_mfma_f32_16x16x32_bf16(pf[1], vf, acc[1][nt], 0, 0, 0);
        }
        __syncthreads();
    }
    // write O = acc / l
    #pragma unroll
    for (int mt = 0; mt < 2; ++mt)
        #pragma unroll
        for (int r = 0; r < 4; ++r) {
            int row = mt * 16 + quad * 4 + r;
            float inv = 1.0f / l_l[row];
            #pragma unroll
            for (int nt = 0; nt < 8; ++nt) {
                int m = q0 + row, d = cb + nt * 16 + l15;
                Ob[(size_t)m * 512 + d] = f2bf(acc[mt][nt][r] * inv);
            }
        }
}

extern "C" void kernel_launch(void* const* d_in, const int* in_sizes, int n_in,
                              void* d_out, int out_size, void* d_ws, size_t ws_size,
                              hipStream_t stream) {
    const float* x     = (const float*)d_in[0];
    const float* gamma = (const float*)d_in[1];
    const float* beta  = (const float*)d_in[2];
    const float* wq    = (const float*)d_in[3];
    const float* bq    = (const float*)d_in[4];
    const float* wk    = (const float*)d_in[5];
    const float* bk    = (const float*)d_in[6];
    const float* wv    = (const float*)d_in[7];
    const float* bv    = (const float*)d_in[8];
    const float* wp    = (const float*)d_in[9];
    const float* bp    = (const float*)d_in[10];
    float* out = (float*)d_out;

    const size_t MC = (size_t)B_SZ * L_SEQ * C_DIM;   // 8,388,608 elems
    const size_t WC = (size_t)C_DIM * C_DIM;          // 262,144 elems
    ushort_t* h   = (ushort_t*)d_ws;
    ushort_t* qb  = h  + MC;
    ushort_t* kb  = qb + MC;
    ushort_t* vb  = kb + MC;
    ushort_t* ob  = vb + MC;
    ushort_t* wqb = ob + MC;
    ushort_t* wkb = wqb + WC;
    ushort_t* wvb = wkb + WC;
    ushort_t* wpb = wvb + WC;
    float* sums   = (float*)(wpb + WC);               // [64][8][2]

    conv_w<<<dim3(512), dim3(256), 0, stream>>>(wq, wk, wv, wp, wqb, wkb, wvb, wpb);
    gn_stats<<<dim3(512), dim3(256), 0, stream>>>(x, sums);
    gn_apply<<<dim3(4096), dim3(256), 0, stream>>>(x, gamma, beta, sums, h);

    dim3 gg(8, 256);   // N/64 = 8, M/64 = 256
    gemm_bias<false><<<gg, dim3(256), 0, stream>>>(h, wqb, bq, nullptr, qb);
    gemm_bias<false><<<gg, dim3(256), 0, stream>>>(h, wkb, bk, nullptr, kb);
    gemm_bias<false><<<gg, dim3(256), 0, stream>>>(h, wvb, bv, nullptr, vb);

    attn_kernel<<<dim3(64, 8), dim3(256), 0, stream>>>(qb, kb, vb, ob);

    gemm_bias<true><<<gg, dim3(256), 0, stream>>>(ob, wpb, bp, h, out);
}

// Round 4
// 756.892 us; speedup vs baseline: 2.0173x; 2.0173x over previous
//
#include <hip/hip_runtime.h>
#include <hip/hip_bf16.h>
#include <cstdint>

typedef unsigned short ushort_t;
typedef __bf16  bf16x8 __attribute__((ext_vector_type(8)));
typedef float   f32x4  __attribute__((ext_vector_type(4)));

#define L_SEQ 2048
#define C_DIM 512
#define B_SZ  8
#define N_GROUPS 8
#define CG 64            // C / GROUPS

__device__ __forceinline__ float bf2f(ushort_t u) {
    union { uint32_t i; float f; } x; x.i = ((uint32_t)u) << 16; return x.f;
}
__device__ __forceinline__ ushort_t f2bf(float f) {
    union { float f; uint32_t i; } x; x.f = f;
    uint32_t i = x.i;
    uint32_t r = (i + 0x7FFFu + ((i >> 16) & 1u)) >> 16;
    return (ushort_t)r;
}

// ---------------- convert 4 weight matrices fp32 -> bf16 ----------------
__global__ __launch_bounds__(256) void conv_w(const float* __restrict__ wq,
                                              const float* __restrict__ wk,
                                              const float* __restrict__ wv,
                                              const float* __restrict__ wp,
                                              ushort_t* __restrict__ owq,
                                              ushort_t* __restrict__ owk,
                                              ushort_t* __restrict__ owv,
                                              ushort_t* __restrict__ owp) {
    int blk = blockIdx.x, tid = threadIdx.x;
    int seg = blk >> 7;
    const float* srcs[4] = {wq, wk, wv, wp};
    ushort_t*    dsts[4] = {owq, owk, owv, owp};
    const float* src = srcs[seg];
    ushort_t*    dst = dsts[seg];
    int off = (blk & 127) * 2048 + tid * 8;
    float4 a = *(const float4*)(src + off);
    float4 b = *(const float4*)(src + off + 4);
    union { uint4 v; ushort_t u[8]; } o;
    o.u[0] = f2bf(a.x); o.u[1] = f2bf(a.y); o.u[2] = f2bf(a.z); o.u[3] = f2bf(a.w);
    o.u[4] = f2bf(b.x); o.u[5] = f2bf(b.y); o.u[6] = f2bf(b.z); o.u[7] = f2bf(b.w);
    *(uint4*)(dst + off) = o.v;
}

// ---------------- GroupNorm stats (fp32 x, split-L partials) ----------------
__global__ __launch_bounds__(256) void gn_stats(const float* __restrict__ x,
                                                float* __restrict__ sums) {
    int bg = blockIdx.x >> 3, sp = blockIdx.x & 7;
    int b = bg >> 3, g = bg & 7;
    int tid = threadIdx.x;
    const float* base = x + ((size_t)b * L_SEQ + sp * 256) * C_DIM + g * CG;
    float s = 0.f, s2 = 0.f;
    #pragma unroll
    for (int it = 0; it < 8; ++it) {
        int i = it * 2048 + tid * 8;
        int l = i >> 6, c = i & 63;
        const float* p = base + (size_t)l * C_DIM + c;
        float4 a = *(const float4*)p;
        float4 bb = *(const float4*)(p + 4);
        s  += a.x + a.y + a.z + a.w + bb.x + bb.y + bb.z + bb.w;
        s2 += a.x*a.x + a.y*a.y + a.z*a.z + a.w*a.w
            + bb.x*bb.x + bb.y*bb.y + bb.z*bb.z + bb.w*bb.w;
    }
    #pragma unroll
    for (int off = 32; off > 0; off >>= 1) { s += __shfl_down(s, off); s2 += __shfl_down(s2, off); }
    __shared__ float rs[4], rs2[4];
    int wave = tid >> 6;
    if ((tid & 63) == 0) { rs[wave] = s; rs2[wave] = s2; }
    __syncthreads();
    if (tid == 0) {
        sums[bg * 16 + sp * 2 + 0] = rs[0] + rs[1] + rs[2] + rs[3];
        sums[bg * 16 + sp * 2 + 1] = rs2[0] + rs2[1] + rs2[2] + rs2[3];
    }
}

// ---------------- GroupNorm apply: fp32 x -> bf16 h ----------------
__global__ __launch_bounds__(256) void gn_apply(const float* __restrict__ x,
                                                const float* __restrict__ gamma,
                                                const float* __restrict__ beta,
                                                const float* __restrict__ sums,
                                                ushort_t* __restrict__ h) {
    size_t e = ((size_t)blockIdx.x * 256 + threadIdx.x) * 8;
    int c = (int)(e % C_DIM);
    size_t bl = e / C_DIM;
    int b = (int)(bl / L_SEQ);
    int g = c >> 6;
    int bg = b * 8 + g;
    float s = 0.f, s2 = 0.f;
    #pragma unroll
    for (int sp = 0; sp < 8; ++sp) { s += sums[bg * 16 + sp * 2]; s2 += sums[bg * 16 + sp * 2 + 1]; }
    const float N = (float)(L_SEQ * CG);
    float mean = s / N;
    float var  = s2 / N - mean * mean;
    float rstd = rsqrtf(var + 1e-3f);
    float4 a = *(const float4*)(x + e);
    float4 bb = *(const float4*)(x + e + 4);
    float xf[8] = {a.x, a.y, a.z, a.w, bb.x, bb.y, bb.z, bb.w};
    union { uint4 v; ushort_t u[8]; } o;
    #pragma unroll
    for (int i = 0; i < 8; ++i)
        o.u[i] = f2bf((xf[i] - mean) * rstd * gamma[c + i] + beta[c + i]);
    *(uint4*)(h + e) = o.v;
}

// ---------------- GEMM: out[m][n] = sum_k A[m][k] W[k][n] + bias[n] (+ res[m][n]) ----------------
template<bool F32OUT>
__global__ __launch_bounds__(256) void gemm_bias(const ushort_t* __restrict__ A,
                                                 const ushort_t* __restrict__ W,
                                                 const float* __restrict__ bias,
                                                 const ushort_t* __restrict__ res,
                                                 void* __restrict__ outv) {
    __shared__ ushort_t As[64][40];
    __shared__ ushort_t Bt[64][40];
    int tid = threadIdx.x;
    int m0 = blockIdx.y * 64, n0 = blockIdx.x * 64;
    int lane = tid & 63, w = tid >> 6;
    int wm = w >> 1, wn = w & 1;
    int l15 = lane & 15, quad = lane >> 4;
    f32x4 acc[2][2] = {};
    int arow = tid >> 2, acol = (tid & 3) * 8;
    int brow = tid >> 3, bcol = (tid & 7) * 8;
    for (int k0 = 0; k0 < 512; k0 += 32) {
        union { uint4 v; ushort_t u[8]; } da, db;
        da.v = *(const uint4*)(A + (size_t)(m0 + arow) * 512 + k0 + acol);
        db.v = *(const uint4*)(W + (size_t)(k0 + brow) * 512 + n0 + bcol);
        *(uint4*)&As[arow][acol] = da.v;
        #pragma unroll
        for (int e = 0; e < 8; ++e) Bt[bcol + e][brow] = db.u[e];
        __syncthreads();
        bf16x8 af0 = *(const bf16x8*)&As[wm * 32 + l15][quad * 8];
        bf16x8 af1 = *(const bf16x8*)&As[wm * 32 + 16 + l15][quad * 8];
        bf16x8 bf0 = *(const bf16x8*)&Bt[wn * 32 + l15][quad * 8];
        bf16x8 bf1 = *(const bf16x8*)&Bt[wn * 32 + 16 + l15][quad * 8];
        acc[0][0] = __builtin_amdgcn_mfma_f32_16x16x32_bf16(af0, bf0, acc[0][0], 0, 0, 0);
        acc[0][1] = __builtin_amdgcn_mfma_f32_16x16x32_bf16(af0, bf1, acc[0][1], 0, 0, 0);
        acc[1][0] = __builtin_amdgcn_mfma_f32_16x16x32_bf16(af1, bf0, acc[1][0], 0, 0, 0);
        acc[1][1] = __builtin_amdgcn_mfma_f32_16x16x32_bf16(af1, bf1, acc[1][1], 0, 0, 0);
        __syncthreads();
    }
    #pragma unroll
    for (int mt = 0; mt < 2; ++mt)
        #pragma unroll
        for (int nt = 0; nt < 2; ++nt)
            #pragma unroll
            for (int r = 0; r < 4; ++r) {
                int m = m0 + wm * 32 + mt * 16 + quad * 4 + r;
                int n = n0 + wn * 32 + nt * 16 + l15;
                float v = acc[mt][nt][r] + bias[n];
                if (res) v += bf2f(res[(size_t)m * 512 + n]);
                if (F32OUT) ((float*)outv)[(size_t)m * 512 + n] = v;
                else        ((ushort_t*)outv)[(size_t)m * 512 + n] = f2bf(v);
            }
}

// ---------------- one-time V transpose: V[b][l][d] -> vT[b][d][l] ----------------
// grid (32 l-tiles, 8 d-tiles, 8 batches), 256 thr, 64x64 tiles.
__global__ __launch_bounds__(256) void transpose_v(const ushort_t* __restrict__ V,
                                                   ushort_t* __restrict__ vT) {
    __shared__ ushort_t Ts[64][72];   // pad 64->72: phase-1 b128 writes 2-way (free)
    int tid = threadIdx.x;
    int l0 = blockIdx.x * 64, d0 = blockIdx.y * 64, b = blockIdx.z;
    const ushort_t* Vb = V + (size_t)b * L_SEQ * C_DIM;
    #pragma unroll
    for (int i = 0; i < 2; ++i) {
        int idx = tid * 2 + i;
        int row = idx >> 3, c8 = (idx & 7) * 8;
        *(uint4*)&Ts[row][c8] = *(const uint4*)(Vb + (size_t)(l0 + row) * 512 + d0 + c8);
    }
    __syncthreads();
    int dr = tid >> 2, lc = (tid & 3) * 16;
    union { uint4 v[2]; ushort_t u[16]; } o;
    #pragma unroll
    for (int j = 0; j < 16; ++j) o.u[j] = Ts[lc + j][dr];
    ushort_t* dst = vT + ((size_t)b * C_DIM + d0 + dr) * L_SEQ + l0 + lc;
    *(uint4*)dst = o.v[0];
    *(uint4*)(dst + 8) = o.v[1];
}

// ---------------- Flash attention v2: Q-row split, parallel softmax, no loop barriers --------
// grid 256 (1-D): b = idx&7 (batch<->XCD for L2 locality), qt = idx>>3 (0..31).
// Block 256 thr = 4 waves; wave owns 16 q-rows. BK=64 keys/iter, 32 iters.
// K B-frags + vT B-frags straight from global (per-batch K+vT = 4MB = one XCD L2).
__global__ __launch_bounds__(256) void attn2(const ushort_t* __restrict__ Q,
                                             const ushort_t* __restrict__ K,
                                             const ushort_t* __restrict__ vT,
                                             ushort_t* __restrict__ O) {
    __shared__ ushort_t Ps[4][16][72];   // per-wave P buffer (C-layout -> A-layout)
    int tid = threadIdx.x;
    int lane = tid & 63, w = tid >> 6;
    int l15 = lane & 15, quad = lane >> 4;
    int b  = blockIdx.x & 7;
    int qt = blockIdx.x >> 3;
    int qr0 = qt * 64 + w * 16;
    const float scale = 0.044194173824159216f;  // 512^-0.5
    const ushort_t* Qb = Q + (size_t)b * L_SEQ * C_DIM;
    const ushort_t* Kb = K + (size_t)b * L_SEQ * C_DIM;
    const ushort_t* Vt = vT + (size_t)b * C_DIM * L_SEQ;
    ushort_t* Ob = O + (size_t)b * L_SEQ * C_DIM;

    // persistent Q fragments: A[m=l15][k=ks*32+quad*8+j]  (64 VGPRs)
    bf16x8 qf[16];
    #pragma unroll
    for (int ks = 0; ks < 16; ++ks)
        qf[ks] = *(const bf16x8*)(Qb + (size_t)(qr0 + l15) * 512 + ks * 32 + quad * 8);

    f32x4 acc[32];   // O accum: 16 q-rows x 512 d (C-layout per 16x16 tile)
    #pragma unroll
    for (int i = 0; i < 32; ++i) acc[i] = (f32x4){0.f, 0.f, 0.f, 0.f};
    float m_r[4] = {-1e30f, -1e30f, -1e30f, -1e30f};
    float l_r[4] = {0.f, 0.f, 0.f, 0.f};

    for (int kt = 0; kt < 32; ++kt) {
        int k0 = kt * 64;
        // ---- S = Q @ K^T for 16 q x 64 keys (full K-dim, no cross-wave reduce)
        f32x4 sacc[4];
        #pragma unroll
        for (int nt = 0; nt < 4; ++nt) sacc[nt] = (f32x4){0.f, 0.f, 0.f, 0.f};
        #pragma unroll
        for (int nt = 0; nt < 4; ++nt) {
            const ushort_t* kp = Kb + (size_t)(k0 + nt * 16 + l15) * 512 + quad * 8;
            #pragma unroll
            for (int ks = 0; ks < 16; ++ks) {
                bf16x8 kf = *(const bf16x8*)(kp + ks * 32);
                sacc[nt] = __builtin_amdgcn_mfma_f32_16x16x32_bf16(qf[ks], kf, sacc[nt], 0, 0, 0);
            }
        }
        // ---- online softmax, all lanes parallel (row = quad*4+r, cols spread over l15)
        float alpha[4];
        #pragma unroll
        for (int r = 0; r < 4; ++r) {
            float mx = fmaxf(fmaxf(sacc[0][r], sacc[1][r]), fmaxf(sacc[2][r], sacc[3][r]));
            #pragma unroll
            for (int off = 1; off < 16; off <<= 1)
                mx = fmaxf(mx, __shfl_xor(mx, off, 64));
            mx *= scale;
            float mn = fmaxf(m_r[r], mx);
            alpha[r] = __expf(m_r[r] - mn);
            m_r[r] = mn;
            float rs = 0.f;
            #pragma unroll
            for (int nt = 0; nt < 4; ++nt) {
                ushort_t pb = f2bf(__expf(sacc[nt][r] * scale - mn));
                Ps[w][quad * 4 + r][nt * 16 + l15] = pb;
                rs += bf2f(pb);
            }
            #pragma unroll
            for (int off = 1; off < 16; off <<= 1)
                rs += __shfl_xor(rs, off, 64);
            l_r[r] = l_r[r] * alpha[r] + rs;
        }
        // ---- rescale O accum (C-layout row mapping matches r)
        #pragma unroll
        for (int nt = 0; nt < 32; ++nt) {
            acc[nt][0] *= alpha[0]; acc[nt][1] *= alpha[1];
            acc[nt][2] *= alpha[2]; acc[nt][3] *= alpha[3];
        }
        // ---- P (A-layout from per-wave LDS; intra-wave RAW, no barrier needed)
        bf16x8 pf0 = *(const bf16x8*)&Ps[w][l15][quad * 8];
        bf16x8 pf1 = *(const bf16x8*)&Ps[w][l15][32 + quad * 8];
        // ---- O += P @ V : 32 d-tiles x 2 k-steps, V^T rows direct from global
        #pragma unroll
        for (int nt = 0; nt < 32; ++nt) {
            const ushort_t* vp = Vt + (size_t)(nt * 16 + l15) * L_SEQ + k0 + quad * 8;
            bf16x8 vf0 = *(const bf16x8*)vp;
            bf16x8 vf1 = *(const bf16x8*)(vp + 32);
            acc[nt] = __builtin_amdgcn_mfma_f32_16x16x32_bf16(pf0, vf0, acc[nt], 0, 0, 0);
            acc[nt] = __builtin_amdgcn_mfma_f32_16x16x32_bf16(pf1, vf1, acc[nt], 0, 0, 0);
        }
    }
    // ---- write O = acc / l
    #pragma unroll
    for (int r = 0; r < 4; ++r) {
        float inv = 1.0f / l_r[r];
        int m = qr0 + quad * 4 + r;
        #pragma unroll
        for (int nt = 0; nt < 32; ++nt)
            Ob[(size_t)m * 512 + nt * 16 + l15] = f2bf(acc[nt][r] * inv);
    }
}

extern "C" void kernel_launch(void* const* d_in, const int* in_sizes, int n_in,
                              void* d_out, int out_size, void* d_ws, size_t ws_size,
                              hipStream_t stream) {
    const float* x     = (const float*)d_in[0];
    const float* gamma = (const float*)d_in[1];
    const float* beta  = (const float*)d_in[2];
    const float* wq    = (const float*)d_in[3];
    const float* bq    = (const float*)d_in[4];
    const float* wk    = (const float*)d_in[5];
    const float* bk    = (const float*)d_in[6];
    const float* wv    = (const float*)d_in[7];
    const float* bv    = (const float*)d_in[8];
    const float* wp    = (const float*)d_in[9];
    const float* bp    = (const float*)d_in[10];
    float* out = (float*)d_out;

    const size_t MC = (size_t)B_SZ * L_SEQ * C_DIM;   // 8,388,608 elems
    const size_t WC = (size_t)C_DIM * C_DIM;
    ushort_t* h    = (ushort_t*)d_ws;
    ushort_t* qb   = h    + MC;
    ushort_t* kb   = qb   + MC;
    ushort_t* vbuf = kb   + MC;   // V, then reused as attention output O
    ushort_t* vtb  = vbuf + MC;   // V^T [b][d][l]
    ushort_t* wqb  = vtb  + MC;
    ushort_t* wkb  = wqb + WC;
    ushort_t* wvb  = wkb + WC;
    ushort_t* wpb  = wvb + WC;
    float* sums    = (float*)(wpb + WC);

    conv_w<<<dim3(512), dim3(256), 0, stream>>>(wq, wk, wv, wp, wqb, wkb, wvb, wpb);
    gn_stats<<<dim3(512), dim3(256), 0, stream>>>(x, sums);
    gn_apply<<<dim3(4096), dim3(256), 0, stream>>>(x, gamma, beta, sums, h);

    dim3 gg(8, 256);
    gemm_bias<false><<<gg, dim3(256), 0, stream>>>(h, wqb, bq, nullptr, qb);
    gemm_bias<false><<<gg, dim3(256), 0, stream>>>(h, wkb, bk, nullptr, kb);
    gemm_bias<false><<<gg, dim3(256), 0, stream>>>(h, wvb, bv, nullptr, vbuf);

    transpose_v<<<dim3(32, 8, 8), dim3(256), 0, stream>>>(vbuf, vtb);

    attn2<<<dim3(256), dim3(256), 0, stream>>>(qb, kb, vtb, vbuf);  // O -> vbuf (V dead)

    gemm_bias<true><<<gg, dim3(256), 0, stream>>>(vbuf, wpb, bp, h, out);
}

// Round 5
// 568.858 us; speedup vs baseline: 2.6841x; 1.3305x over previous
//
#include <hip/hip_runtime.h>
#include <hip/hip_bf16.h>
#include <cstdint>

typedef unsigned short ushort_t;
typedef __bf16  bf16x8 __attribute__((ext_vector_type(8)));
typedef float   f32x4  __attribute__((ext_vector_type(4)));

#define L_SEQ 2048
#define C_DIM 512
#define B_SZ  8
#define N_GROUPS 8
#define CG 64            // C / GROUPS

__device__ __forceinline__ float bf2f(ushort_t u) {
    union { uint32_t i; float f; } x; x.i = ((uint32_t)u) << 16; return x.f;
}
__device__ __forceinline__ ushort_t f2bf(float f) {
    union { float f; uint32_t i; } x; x.f = f;
    uint32_t i = x.i;
    uint32_t r = (i + 0x7FFFu + ((i >> 16) & 1u)) >> 16;
    return (ushort_t)r;
}

// async global->LDS, 16B per lane: lds dst = base + lane*16, global src = per-lane ptr
__device__ __forceinline__ void gl_lds16(const ushort_t* g, ushort_t* l) {
    __builtin_amdgcn_global_load_lds(
        (const __attribute__((address_space(1))) unsigned int*)g,
        (__attribute__((address_space(3))) unsigned int*)l, 16, 0, 0);
}

// ---------------- convert 4 weight matrices fp32 -> bf16 ----------------
__global__ __launch_bounds__(256) void conv_w(const float* __restrict__ wq,
                                              const float* __restrict__ wk,
                                              const float* __restrict__ wv,
                                              const float* __restrict__ wp,
                                              ushort_t* __restrict__ owq,
                                              ushort_t* __restrict__ owk,
                                              ushort_t* __restrict__ owv,
                                              ushort_t* __restrict__ owp) {
    int blk = blockIdx.x, tid = threadIdx.x;
    int seg = blk >> 7;
    const float* srcs[4] = {wq, wk, wv, wp};
    ushort_t*    dsts[4] = {owq, owk, owv, owp};
    const float* src = srcs[seg];
    ushort_t*    dst = dsts[seg];
    int off = (blk & 127) * 2048 + tid * 8;
    float4 a = *(const float4*)(src + off);
    float4 b = *(const float4*)(src + off + 4);
    union { uint4 v; ushort_t u[8]; } o;
    o.u[0] = f2bf(a.x); o.u[1] = f2bf(a.y); o.u[2] = f2bf(a.z); o.u[3] = f2bf(a.w);
    o.u[4] = f2bf(b.x); o.u[5] = f2bf(b.y); o.u[6] = f2bf(b.z); o.u[7] = f2bf(b.w);
    *(uint4*)(dst + off) = o.v;
}

// ---------------- GroupNorm stats (fp32 x, split-L partials) ----------------
__global__ __launch_bounds__(256) void gn_stats(const float* __restrict__ x,
                                                float* __restrict__ sums) {
    int bg = blockIdx.x >> 3, sp = blockIdx.x & 7;
    int b = bg >> 3, g = bg & 7;
    int tid = threadIdx.x;
    const float* base = x + ((size_t)b * L_SEQ + sp * 256) * C_DIM + g * CG;
    float s = 0.f, s2 = 0.f;
    #pragma unroll
    for (int it = 0; it < 8; ++it) {
        int i = it * 2048 + tid * 8;
        int l = i >> 6, c = i & 63;
        const float* p = base + (size_t)l * C_DIM + c;
        float4 a = *(const float4*)p;
        float4 bb = *(const float4*)(p + 4);
        s  += a.x + a.y + a.z + a.w + bb.x + bb.y + bb.z + bb.w;
        s2 += a.x*a.x + a.y*a.y + a.z*a.z + a.w*a.w
            + bb.x*bb.x + bb.y*bb.y + bb.z*bb.z + bb.w*bb.w;
    }
    #pragma unroll
    for (int off = 32; off > 0; off >>= 1) { s += __shfl_down(s, off); s2 += __shfl_down(s2, off); }
    __shared__ float rs[4], rs2[4];
    int wave = tid >> 6;
    if ((tid & 63) == 0) { rs[wave] = s; rs2[wave] = s2; }
    __syncthreads();
    if (tid == 0) {
        sums[bg * 16 + sp * 2 + 0] = rs[0] + rs[1] + rs[2] + rs[3];
        sums[bg * 16 + sp * 2 + 1] = rs2[0] + rs2[1] + rs2[2] + rs2[3];
    }
}

// ---------------- GroupNorm apply: fp32 x -> bf16 h ----------------
__global__ __launch_bounds__(256) void gn_apply(const float* __restrict__ x,
                                                const float* __restrict__ gamma,
                                                const float* __restrict__ beta,
                                                const float* __restrict__ sums,
                                                ushort_t* __restrict__ h) {
    size_t e = ((size_t)blockIdx.x * 256 + threadIdx.x) * 8;
    int c = (int)(e % C_DIM);
    size_t bl = e / C_DIM;
    int b = (int)(bl / L_SEQ);
    int g = c >> 6;
    int bg = b * 8 + g;
    float s = 0.f, s2 = 0.f;
    #pragma unroll
    for (int sp = 0; sp < 8; ++sp) { s += sums[bg * 16 + sp * 2]; s2 += sums[bg * 16 + sp * 2 + 1]; }
    const float N = (float)(L_SEQ * CG);
    float mean = s / N;
    float var  = s2 / N - mean * mean;
    float rstd = rsqrtf(var + 1e-3f);
    float4 a = *(const float4*)(x + e);
    float4 bb = *(const float4*)(x + e + 4);
    float xf[8] = {a.x, a.y, a.z, a.w, bb.x, bb.y, bb.z, bb.w};
    union { uint4 v; ushort_t u[8]; } o;
    #pragma unroll
    for (int i = 0; i < 8; ++i)
        o.u[i] = f2bf((xf[i] - mean) * rstd * gamma[c + i] + beta[c + i]);
    *(uint4*)(h + e) = o.v;
}

// ---------------- GEMM: out[m][n] = sum_k A[m][k] W[k][n] + bias[n] (+ res[m][n]) ----------------
template<bool F32OUT>
__global__ __launch_bounds__(256) void gemm_bias(const ushort_t* __restrict__ A,
                                                 const ushort_t* __restrict__ W,
                                                 const float* __restrict__ bias,
                                                 const ushort_t* __restrict__ res,
                                                 void* __restrict__ outv) {
    __shared__ ushort_t As[64][40];
    __shared__ ushort_t Bt[64][40];
    int tid = threadIdx.x;
    int m0 = blockIdx.y * 64, n0 = blockIdx.x * 64;
    int lane = tid & 63, w = tid >> 6;
    int wm = w >> 1, wn = w & 1;
    int l15 = lane & 15, quad = lane >> 4;
    f32x4 acc[2][2] = {};
    int arow = tid >> 2, acol = (tid & 3) * 8;
    int brow = tid >> 3, bcol = (tid & 7) * 8;
    for (int k0 = 0; k0 < 512; k0 += 32) {
        union { uint4 v; ushort_t u[8]; } da, db;
        da.v = *(const uint4*)(A + (size_t)(m0 + arow) * 512 + k0 + acol);
        db.v = *(const uint4*)(W + (size_t)(k0 + brow) * 512 + n0 + bcol);
        *(uint4*)&As[arow][acol] = da.v;
        #pragma unroll
        for (int e = 0; e < 8; ++e) Bt[bcol + e][brow] = db.u[e];
        __syncthreads();
        bf16x8 af0 = *(const bf16x8*)&As[wm * 32 + l15][quad * 8];
        bf16x8 af1 = *(const bf16x8*)&As[wm * 32 + 16 + l15][quad * 8];
        bf16x8 bf0 = *(const bf16x8*)&Bt[wn * 32 + l15][quad * 8];
        bf16x8 bf1 = *(const bf16x8*)&Bt[wn * 32 + 16 + l15][quad * 8];
        acc[0][0] = __builtin_amdgcn_mfma_f32_16x16x32_bf16(af0, bf0, acc[0][0], 0, 0, 0);
        acc[0][1] = __builtin_amdgcn_mfma_f32_16x16x32_bf16(af0, bf1, acc[0][1], 0, 0, 0);
        acc[1][0] = __builtin_amdgcn_mfma_f32_16x16x32_bf16(af1, bf0, acc[1][0], 0, 0, 0);
        acc[1][1] = __builtin_amdgcn_mfma_f32_16x16x32_bf16(af1, bf1, acc[1][1], 0, 0, 0);
        __syncthreads();
    }
    #pragma unroll
    for (int mt = 0; mt < 2; ++mt)
        #pragma unroll
        for (int nt = 0; nt < 2; ++nt)
            #pragma unroll
            for (int r = 0; r < 4; ++r) {
                int m = m0 + wm * 32 + mt * 16 + quad * 4 + r;
                int n = n0 + wn * 32 + nt * 16 + l15;
                float v = acc[mt][nt][r] + bias[n];
                if (res) v += bf2f(res[(size_t)m * 512 + n]);
                if (F32OUT) ((float*)outv)[(size_t)m * 512 + n] = v;
                else        ((ushort_t*)outv)[(size_t)m * 512 + n] = f2bf(v);
            }
}

// ---------------- one-time V transpose: V[b][l][d] -> vT[b][d][l] ----------------
__global__ __launch_bounds__(256) void transpose_v(const ushort_t* __restrict__ V,
                                                   ushort_t* __restrict__ vT) {
    __shared__ ushort_t Ts[64][72];
    int tid = threadIdx.x;
    int l0 = blockIdx.x * 64, d0 = blockIdx.y * 64, b = blockIdx.z;
    const ushort_t* Vb = V + (size_t)b * L_SEQ * C_DIM;
    #pragma unroll
    for (int i = 0; i < 2; ++i) {
        int idx = tid * 2 + i;
        int row = idx >> 3, c8 = (idx & 7) * 8;
        *(uint4*)&Ts[row][c8] = *(const uint4*)(Vb + (size_t)(l0 + row) * 512 + d0 + c8);
    }
    __syncthreads();
    int dr = tid >> 2, lc = (tid & 3) * 16;
    union { uint4 v[2]; ushort_t u[16]; } o;
    #pragma unroll
    for (int j = 0; j < 16; ++j) o.u[j] = Ts[lc + j][dr];
    ushort_t* dst = vT + ((size_t)b * C_DIM + d0 + dr) * L_SEQ + l0 + lc;
    *(uint4*)dst = o.v[0];
    *(uint4*)(dst + 8) = o.v[1];
}

// ---------------- Flash attention v3: LDS-staged K/V, double-buffered prefetch ------------
// grid 256: b = idx&7 (batch<->XCD), qt = idx>>3. 4 waves x 16 q-rows, BK=32, 64 iters.
// Per iter: async global_load_lds K-tile(next) + reg-prefetch vT-tile(next),
// compute QK/softmax/PV from current buffers, ds_write vT regs, one barrier.
__global__ __launch_bounds__(256) void attn3(const ushort_t* __restrict__ Q,
                                             const ushort_t* __restrict__ K,
                                             const ushort_t* __restrict__ vT,
                                             ushort_t* __restrict__ O) {
    __shared__ ushort_t Ks[2][32][520];   // [key][c] pad 512->520 (66.6 KB)
    __shared__ ushort_t Vs[2][512][36];   // [d][k]  pad 32->36  (73.7 KB)
    __shared__ ushort_t Ps[4][16][36];    // per-wave P, [q][k] pad 32->36 (4.6 KB)
    int tid = threadIdx.x;
    int lane = tid & 63, w = tid >> 6;
    int l15 = lane & 15, quad = lane >> 4;
    int b  = blockIdx.x & 7;
    int qt = blockIdx.x >> 3;
    int qr0 = qt * 64 + w * 16;
    const float scale2 = 0.044194173824159216f * 1.4426950408889634f;  // 512^-.5 * log2(e)
    const ushort_t* Qb = Q + (size_t)b * L_SEQ * C_DIM;
    const ushort_t* Kb = K + (size_t)b * L_SEQ * C_DIM;
    const ushort_t* Vt = vT + (size_t)b * C_DIM * L_SEQ;
    ushort_t* Ob = O + (size_t)b * L_SEQ * C_DIM;

    int vrow = tid >> 2;             // V-staging: row within 64-row group
    int vcol = (tid & 3) * 8;        // 8-elem column offset

    // persistent Q fragments: A[m=l15][k=ks*32+quad*8+j]  (64 VGPRs)
    bf16x8 qf[16];
    #pragma unroll
    for (int ks = 0; ks < 16; ++ks)
        qf[ks] = *(const bf16x8*)(Qb + (size_t)(qr0 + l15) * 512 + ks * 32 + quad * 8);

    f32x4 acc[32];
    #pragma unroll
    for (int i = 0; i < 32; ++i) acc[i] = (f32x4){0.f, 0.f, 0.f, 0.f};
    float m_r[4] = {-1e30f, -1e30f, -1e30f, -1e30f};
    float l_r[4] = {0.f, 0.f, 0.f, 0.f};

    // ---- prologue: stage tile 0 into buffer 0
    #pragma unroll
    for (int i = 0; i < 8; ++i) {
        int row = w * 8 + i;
        gl_lds16(Kb + (size_t)row * 512 + lane * 8, &Ks[0][row][0]);
    }
    #pragma unroll
    for (int r8 = 0; r8 < 8; ++r8) {
        int d = r8 * 64 + vrow;
        uint4 v = *(const uint4*)(Vt + (size_t)d * L_SEQ + vcol);
        *(uint4*)&Vs[0][d][vcol] = v;
    }
    __syncthreads();

    for (int kt = 0; kt < 64; ++kt) {
        int cur = kt & 1, nxt = cur ^ 1;
        int k0n = (kt + 1) * 32;
        // ---- async prefetch next K tile into other buffer
        if (kt < 63) {
            #pragma unroll
            for (int i = 0; i < 8; ++i) {
                int row = w * 8 + i;
                gl_lds16(Kb + (size_t)(k0n + row) * 512 + lane * 8, &Ks[nxt][row][0]);
            }
        }
        // ---- prefetch next vT tile into registers (latency spans compute)
        uint4 pv[8];
        if (kt < 63) {
            #pragma unroll
            for (int r8 = 0; r8 < 8; ++r8) {
                int d = r8 * 64 + vrow;
                pv[r8] = *(const uint4*)(Vt + (size_t)d * L_SEQ + k0n + vcol);
            }
        }
        // ---- S = Q @ K^T (16 q x 32 keys) from LDS
        f32x4 sacc[2];
        sacc[0] = (f32x4){0.f, 0.f, 0.f, 0.f};
        sacc[1] = (f32x4){0.f, 0.f, 0.f, 0.f};
        #pragma unroll
        for (int ks = 0; ks < 16; ++ks) {
            bf16x8 kf0 = *(const bf16x8*)&Ks[cur][l15][ks * 32 + quad * 8];
            bf16x8 kf1 = *(const bf16x8*)&Ks[cur][16 + l15][ks * 32 + quad * 8];
            sacc[0] = __builtin_amdgcn_mfma_f32_16x16x32_bf16(qf[ks], kf0, sacc[0], 0, 0, 0);
            sacc[1] = __builtin_amdgcn_mfma_f32_16x16x32_bf16(qf[ks], kf1, sacc[1], 0, 0, 0);
        }
        // ---- online softmax (exp2 domain), all lanes parallel
        float alpha[4];
        #pragma unroll
        for (int r = 0; r < 4; ++r) {
            float mx = fmaxf(sacc[0][r], sacc[1][r]);
            #pragma unroll
            for (int off = 1; off < 16; off <<= 1)
                mx = fmaxf(mx, __shfl_xor(mx, off, 64));
            mx *= scale2;
            float mn = fmaxf(m_r[r], mx);
            alpha[r] = exp2f(m_r[r] - mn);
            m_r[r] = mn;
            float rs = 0.f;
            #pragma unroll
            for (int nt = 0; nt < 2; ++nt) {
                ushort_t pb = f2bf(exp2f(sacc[nt][r] * scale2 - mn));
                Ps[w][quad * 4 + r][nt * 16 + l15] = pb;
                rs += bf2f(pb);
            }
            #pragma unroll
            for (int off = 1; off < 16; off <<= 1)
                rs += __shfl_xor(rs, off, 64);
            l_r[r] = l_r[r] * alpha[r] + rs;
        }
        // ---- rescale O accumulator
        #pragma unroll
        for (int nt = 0; nt < 32; ++nt) {
            acc[nt][0] *= alpha[0]; acc[nt][1] *= alpha[1];
            acc[nt][2] *= alpha[2]; acc[nt][3] *= alpha[3];
        }
        // ---- P A-frag (intra-wave RAW through LDS, no barrier)
        bf16x8 pf = *(const bf16x8*)&Ps[w][l15][quad * 8];
        // ---- O += P @ V from LDS (32 d-tiles)
        #pragma unroll
        for (int nt = 0; nt < 32; ++nt) {
            bf16x8 vf = *(const bf16x8*)&Vs[cur][nt * 16 + l15][quad * 8];
            acc[nt] = __builtin_amdgcn_mfma_f32_16x16x32_bf16(pf, vf, acc[nt], 0, 0, 0);
        }
        // ---- commit prefetched vT regs to LDS, then fence the pipeline
        if (kt < 63) {
            #pragma unroll
            for (int r8 = 0; r8 < 8; ++r8) {
                int d = r8 * 64 + vrow;
                *(uint4*)&Vs[nxt][d][vcol] = pv[r8];
            }
        }
        __syncthreads();   // drains vmcnt (K prefetch) + orders LDS across waves
    }
    // ---- write O = acc / l
    #pragma unroll
    for (int r = 0; r < 4; ++r) {
        float inv = 1.0f / l_r[r];
        int m = qr0 + quad * 4 + r;
        #pragma unroll
        for (int nt = 0; nt < 32; ++nt)
            Ob[(size_t)m * 512 + nt * 16 + l15] = f2bf(acc[nt][r] * inv);
    }
}

extern "C" void kernel_launch(void* const* d_in, const int* in_sizes, int n_in,
                              void* d_out, int out_size, void* d_ws, size_t ws_size,
                              hipStream_t stream) {
    const float* x     = (const float*)d_in[0];
    const float* gamma = (const float*)d_in[1];
    const float* beta  = (const float*)d_in[2];
    const float* wq    = (const float*)d_in[3];
    const float* bq    = (const float*)d_in[4];
    const float* wk    = (const float*)d_in[5];
    const float* bk    = (const float*)d_in[6];
    const float* wv    = (const float*)d_in[7];
    const float* bv    = (const float*)d_in[8];
    const float* wp    = (const float*)d_in[9];
    const float* bp    = (const float*)d_in[10];
    float* out = (float*)d_out;

    const size_t MC = (size_t)B_SZ * L_SEQ * C_DIM;   // 8,388,608 elems
    const size_t WC = (size_t)C_DIM * C_DIM;
    ushort_t* h    = (ushort_t*)d_ws;
    ushort_t* qb   = h    + MC;
    ushort_t* kb   = qb   + MC;
    ushort_t* vbuf = kb   + MC;   // V, then reused as attention output O
    ushort_t* vtb  = vbuf + MC;   // V^T [b][d][l]
    ushort_t* wqb  = vtb  + MC;
    ushort_t* wkb  = wqb + WC;
    ushort_t* wvb  = wkb + WC;
    ushort_t* wpb  = wvb + WC;
    float* sums    = (float*)(wpb + WC);

    conv_w<<<dim3(512), dim3(256), 0, stream>>>(wq, wk, wv, wp, wqb, wkb, wvb, wpb);
    gn_stats<<<dim3(512), dim3(256), 0, stream>>>(x, sums);
    gn_apply<<<dim3(4096), dim3(256), 0, stream>>>(x, gamma, beta, sums, h);

    dim3 gg(8, 256);
    gemm_bias<false><<<gg, dim3(256), 0, stream>>>(h, wqb, bq, nullptr, qb);
    gemm_bias<false><<<gg, dim3(256), 0, stream>>>(h, wkb, bk, nullptr, kb);
    gemm_bias<false><<<gg, dim3(256), 0, stream>>>(h, wvb, bv, nullptr, vbuf);

    transpose_v<<<dim3(32, 8, 8), dim3(256), 0, stream>>>(vbuf, vtb);

    attn3<<<dim3(256), dim3(256), 0, stream>>>(qb, kb, vtb, vbuf);  // O -> vbuf (V dead)

    gemm_bias<true><<<gg, dim3(256), 0, stream>>>(vbuf, wpb, bp, h, out);
}